// Round 5
// baseline (3256.037 us; speedup 1.0000x reference)
//
#include <hip/hip_runtime.h>

#define T 4096

// tanh(x) = 1 - 2/(exp(2x)+1). v_exp_f32 + v_rcp_f32, branch-free, ~1e-6 err.
// Saturates correctly: x>>0 -> e=inf -> rcp=0 -> 1; x<<0 -> e=0 -> 1-2 = -1.
// Exonerated by R2/R3 (identical absmax with/without it -> its error is
// below bf16 rounding even after 4096 recurrent steps).
__device__ __forceinline__ float fast_tanh(float x) {
    float e = __expf(2.0f * x);
    float r = __builtin_amdgcn_rcpf(e + 1.0f);
    return fmaf(-2.0f, r, 1.0f);
}

// ---------------------------------------------------------------------------
// prep: pre[s][t][i] = b_ih0[i] + b_hh0[i] + sum_d W_ih0[i][d] * in[0,t,d]
// Only batch element 0 of x / y matters (reference uses e[0], o[0] only).
// ---------------------------------------------------------------------------
__global__ void prep_kernel(const float* __restrict__ x, const float* __restrict__ y,
                            const float* __restrict__ eW, const float* __restrict__ ebi,
                            const float* __restrict__ ebh,
                            const float* __restrict__ oW, const float* __restrict__ obi,
                            const float* __restrict__ obh,
                            float* __restrict__ pre)
{
    int idx = blockIdx.x * blockDim.x + threadIdx.x;   // 2*T*64 threads
    int i = idx & 63;
    int t = (idx >> 6) & (T - 1);
    int s = idx >> 18;
    const float* in = s ? y : x;          // batch 0 = first T*3 floats
    const float* W  = s ? oW : eW;        // [64][3]
    const float* bi = s ? obi : ebi;
    const float* bh = s ? obh : ebh;
    float v = bi[i] + bh[i]
            + W[i*3+0]*in[t*3+0] + W[i*3+1]*in[t*3+1] + W[i*3+2]*in[t*3+2];
    pre[idx] = v;
}

// ---------------------------------------------------------------------------
// seq: ONE wave (64 lanes) per RNN; lane i owns row i of all three matrices.
// No cross-wave dependencies -> __syncthreads() is a near-free fence.
// Pipeline (q computed from h0[t-1], one step behind layer 0):
//   step t (1..T-1): h0[t]   = tanh(p[t] + Whh0@h0[t-1])
//                    h1[t-1] = tanh(b1 + Wih1@h0[t-1] + Whh1@h1[t-2])
// Double-buffered h0/h1 in LDS; h0[-1]=h1[-1]=0.
// ---------------------------------------------------------------------------
__global__ __launch_bounds__(64, 1) void seq_kernel(
    const float* __restrict__ pre,            // [2][T][64]
    const float* __restrict__ eWhh0, const float* __restrict__ eWih1,
    const float* __restrict__ eWhh1, const float* __restrict__ ebih1,
    const float* __restrict__ ebhh1,
    const float* __restrict__ oWhh0, const float* __restrict__ oWih1,
    const float* __restrict__ oWhh1, const float* __restrict__ obih1,
    const float* __restrict__ obhh1,
    float* __restrict__ hlast)                // [2][64]
{
    const int s    = blockIdx.x;
    const int lane = threadIdx.x;

    __shared__ __align__(16) float h0buf[2][64];
    __shared__ __align__(16) float h1buf[2][64];

    const float* Whh0 = s ? oWhh0 : eWhh0;
    const float* Wih1 = s ? oWih1 : eWih1;
    const float* Whh1 = s ? oWhh1 : eWhh1;
    const float  b1   = s ? (obih1[lane] + obhh1[lane])
                          : (ebih1[lane] + ebhh1[lane]);
    const float* p    = pre + s * T * 64;

    // Rows of the three 64x64 matrices in this lane's registers (unified
    // VGPR/AGPR file: 192 floats fits the 1-wave/SIMD budget without spill).
    float w0[64], wi[64], w1[64];
#pragma unroll
    for (int j = 0; j < 64; ++j) {
        w0[j] = Whh0[lane * 64 + j];
        wi[j] = Wih1[lane * 64 + j];
        w1[j] = Whh1[lane * 64 + j];
    }

    // h1[-1] = 0 (read at t=1 from h1buf[1]); h0 prologue writes h0buf[0].
    h1buf[1][lane] = 0.f;

    // ---- t = 0: h0[0] = tanh(p[0] + Whh0@0) = tanh(p[0]) ----
    h0buf[0][lane] = fast_tanh(p[lane]);
    __syncthreads();

    float p_cur = p[64 + lane];               // p[1]
    float h1_last = 0.f;

    for (int t = 1; t < T; ++t) {
        int tn = (t + 1 < T) ? (t + 1) : (T - 1);
        float p_nxt = p[tn * 64 + lane];      // prefetch (overlaps compute)

        const float4* hv0 = (const float4*)h0buf[(t - 1) & 1];
        const float4* hv1 = (const float4*)h1buf[t & 1];

        float a0 = p_cur, a1 = 0.f, a2 = 0.f, a3 = 0.f;
        float q0 = b1,    q1 = 0.f, q2 = 0.f, q3 = 0.f;
        float c0 = 0.f,   c1 = 0.f, c2 = 0.f, c3 = 0.f;
#pragma unroll
        for (int j4 = 0; j4 < 16; ++j4) {
            float4 v = hv0[j4];
            a0 = fmaf(w0[4*j4+0], v.x, a0);  a1 = fmaf(w0[4*j4+1], v.y, a1);
            a2 = fmaf(w0[4*j4+2], v.z, a2);  a3 = fmaf(w0[4*j4+3], v.w, a3);
            q0 = fmaf(wi[4*j4+0], v.x, q0);  q1 = fmaf(wi[4*j4+1], v.y, q1);
            q2 = fmaf(wi[4*j4+2], v.z, q2);  q3 = fmaf(wi[4*j4+3], v.w, q3);
        }
#pragma unroll
        for (int j4 = 0; j4 < 16; ++j4) {
            float4 u = hv1[j4];
            c0 = fmaf(w1[4*j4+0], u.x, c0);  c1 = fmaf(w1[4*j4+1], u.y, c1);
            c2 = fmaf(w1[4*j4+2], u.z, c2);  c3 = fmaf(w1[4*j4+3], u.w, c3);
        }
        float h0n = fast_tanh((a0 + a1) + (a2 + a3));
        float h1n = fast_tanh(((q0 + q1) + (q2 + q3)) + ((c0 + c1) + (c2 + c3)));

        h0buf[t & 1][lane]       = h0n;       // h0[t]
        h1buf[(t - 1) & 1][lane] = h1n;       // h1[t-1]
        h1_last = h1n;
        p_cur = p_nxt;
        __syncthreads();                      // single-wave: near-free fence
    }

    // ---- tail: h1[T-1] = tanh(b1 + Wih1@h0[T-1] + Whh1@h1[T-2]) ----
    {
        const float4* hv0 = (const float4*)h0buf[(T - 1) & 1];
        const float4* hv1 = (const float4*)h1buf[T & 1];
        float q0 = b1,  q1 = 0.f, q2 = 0.f, q3 = 0.f;
        float c0 = 0.f, c1 = 0.f, c2 = 0.f, c3 = 0.f;
#pragma unroll
        for (int j4 = 0; j4 < 16; ++j4) {
            float4 v = hv0[j4];
            q0 = fmaf(wi[4*j4+0], v.x, q0);  q1 = fmaf(wi[4*j4+1], v.y, q1);
            q2 = fmaf(wi[4*j4+2], v.z, q2);  q3 = fmaf(wi[4*j4+3], v.w, q3);
            float4 u = hv1[j4];
            c0 = fmaf(w1[4*j4+0], u.x, c0);  c1 = fmaf(w1[4*j4+1], u.y, c1);
            c2 = fmaf(w1[4*j4+2], u.z, c2);  c3 = fmaf(w1[4*j4+3], u.w, c3);
        }
        h1_last = fast_tanh(((q0 + q1) + (q2 + q3)) + ((c0 + c1) + (c2 + c3)));
    }

    hlast[s * 64 + lane] = h1_last;
}

// ---------------------------------------------------------------------------
// head: e0 = fce_w@hx + fce_b ; o0 = fco_w@hy + fco_b ; zz=[e0,o0,z];
//       h = relu(fc1_w@zz + fc1_b) ; out = fc2_w@h + fc2_b
// ---------------------------------------------------------------------------
__global__ void head_kernel(const float* __restrict__ hlast,   // [2][64]
                            const float* __restrict__ z,
                            const float* __restrict__ fce_w, const float* __restrict__ fce_b,
                            const float* __restrict__ fco_w, const float* __restrict__ fco_b,
                            const float* __restrict__ fc1_w, const float* __restrict__ fc1_b,
                            const float* __restrict__ fc2_w, const float* __restrict__ fc2_b,
                            float* __restrict__ out)            // [5]
{
    const int lane = threadIdx.x;   // 64 threads
    __shared__ float zz[9];
    __shared__ float hh[64];

    if (lane < 2) {
        float sacc = fce_b[lane];
        for (int j = 0; j < 64; ++j) sacc += fce_w[lane * 64 + j] * hlast[j];
        zz[lane] = sacc;
    } else if (lane < 4) {
        int r = lane - 2;
        float sacc = fco_b[r];
        for (int j = 0; j < 64; ++j) sacc += fco_w[r * 64 + j] * hlast[64 + j];
        zz[lane] = sacc;
    } else if (lane < 9) {
        zz[lane] = z[lane - 4];
    }
    __syncthreads();

    float sacc = fc1_b[lane];
#pragma unroll
    for (int j = 0; j < 9; ++j) sacc += fc1_w[lane * 9 + j] * zz[j];
    hh[lane] = fmaxf(sacc, 0.f);
    __syncthreads();

    if (lane < 5) {
        float o = fc2_b[lane];
        for (int i = 0; i < 64; ++i) o += fc2_w[lane * 64 + i] * hh[i];
        out[lane] = o;
    }
}

// ---------------------------------------------------------------------------
extern "C" void kernel_launch(void* const* d_in, const int* in_sizes, int n_in,
                              void* d_out, int out_size, void* d_ws, size_t ws_size,
                              hipStream_t stream)
{
    const float* x      = (const float*)d_in[0];
    const float* y      = (const float*)d_in[1];
    const float* z      = (const float*)d_in[2];
    const float* e_Wih0 = (const float*)d_in[3];
    const float* e_Whh0 = (const float*)d_in[4];
    const float* e_bih0 = (const float*)d_in[5];
    const float* e_bhh0 = (const float*)d_in[6];
    const float* e_Wih1 = (const float*)d_in[7];
    const float* e_Whh1 = (const float*)d_in[8];
    const float* e_bih1 = (const float*)d_in[9];
    const float* e_bhh1 = (const float*)d_in[10];
    const float* o_Wih0 = (const float*)d_in[11];
    const float* o_Whh0 = (const float*)d_in[12];
    const float* o_bih0 = (const float*)d_in[13];
    const float* o_bhh0 = (const float*)d_in[14];
    const float* o_Wih1 = (const float*)d_in[15];
    const float* o_Whh1 = (const float*)d_in[16];
    const float* o_bih1 = (const float*)d_in[17];
    const float* o_bhh1 = (const float*)d_in[18];
    const float* fce_w  = (const float*)d_in[19];
    const float* fce_b  = (const float*)d_in[20];
    const float* fco_w  = (const float*)d_in[21];
    const float* fco_b  = (const float*)d_in[22];
    const float* fc1_w  = (const float*)d_in[23];
    const float* fc1_b  = (const float*)d_in[24];
    const float* fc2_w  = (const float*)d_in[25];
    const float* fc2_b  = (const float*)d_in[26];

    float* pre   = (float*)d_ws;            // 2*T*64 floats = 2 MB
    float* hlast = pre + 2 * T * 64;        // 128 floats
    float* out   = (float*)d_out;

    prep_kernel<<<(2 * T * 64) / 256, 256, 0, stream>>>(
        x, y, e_Wih0, e_bih0, e_bhh0, o_Wih0, o_bih0, o_bhh0, pre);

    seq_kernel<<<2, 64, 0, stream>>>(
        pre,
        e_Whh0, e_Wih1, e_Whh1, e_bih1, e_bhh1,
        o_Whh0, o_Wih1, o_Whh1, o_bih1, o_bhh1,
        hlast);

    head_kernel<<<1, 64, 0, stream>>>(
        hlast, z, fce_w, fce_b, fco_w, fco_b, fc1_w, fc1_b, fc2_w, fc2_b, out);
}

// Round 6
// 2713.947 us; speedup vs baseline: 1.1997x; 1.1997x over previous
//
#include <hip/hip_runtime.h>

#define T 4096

// tanh(x) = 1 - 2/(exp(2x)+1). v_exp_f32 + v_rcp_f32, branch-free, ~30 cyc.
// Exonerated by R2 vs R3: identical absmax with/without -> error below bf16
// rounding even through 4096 recurrent steps. Saturates correctly at +/-1.
__device__ __forceinline__ float fast_tanh(float x) {
    float e = __expf(2.0f * x);
    float r = __builtin_amdgcn_rcpf(e + 1.0f);
    return fmaf(-2.0f, r, 1.0f);
}

// ---------------------------------------------------------------------------
// prep: pre[s][t][i] = b_ih0[i] + b_hh0[i] + sum_d W_ih0[i][d] * in[0,t,d]
// Only batch element 0 of x / y matters (reference uses e[0], o[0] only).
// ---------------------------------------------------------------------------
__global__ void prep_kernel(const float* __restrict__ x, const float* __restrict__ y,
                            const float* __restrict__ eW, const float* __restrict__ ebi,
                            const float* __restrict__ ebh,
                            const float* __restrict__ oW, const float* __restrict__ obi,
                            const float* __restrict__ obh,
                            float* __restrict__ pre)
{
    int idx = blockIdx.x * blockDim.x + threadIdx.x;   // 2*T*64 threads
    int i = idx & 63;
    int t = (idx >> 6) & (T - 1);
    int s = idx >> 18;
    const float* in = s ? y : x;          // batch 0 = first T*3 floats
    const float* W  = s ? oW : eW;        // [64][3]
    const float* bi = s ? obi : ebi;
    const float* bh = s ? obh : ebh;
    float v = bi[i] + bh[i]
            + W[i*3+0]*in[t*3+0] + W[i*3+1]*in[t*3+1] + W[i*3+2]*in[t*3+2];
    pre[idx] = v;
}

// ---------------------------------------------------------------------------
// seq: one block of 2 waves per RNN, 1 barrier per pipeline slot (R4 indexing,
// proven correct). Per-slot ordering puts each wave's recurrent chain FIRST,
// publishes to LDS, then does off-path FMAs from register-cached h values.
//   wave0 @ slot t:  h0[t]   = tanh(p[t] + Whh0@h0[t-1])            (t < T)
//                    qp0[t-1]= b1 + Wih1[:,0:32]@h0[t-1][0:32]      (t <= T)
//   wave1 @ slot t:  h1[t-2] = tanh(qp0[t-2] + qp1[t-2] + Whh1@h1[t-3]) (t>=2)
//                    qp1[t-1]= Wih1[:,32:]@h0[t-1][32:]             (1<=t<=T)
// Weights: 96 floats/wave -> stays in VGPRs (R5 showed 192 floats/wave
// overflows into AGPRs and regresses).
// ---------------------------------------------------------------------------
__global__ __launch_bounds__(128, 1) void seq_kernel(
    const float* __restrict__ pre,            // [2][T][64]
    const float* __restrict__ eWhh0, const float* __restrict__ eWih1,
    const float* __restrict__ eWhh1, const float* __restrict__ ebih1,
    const float* __restrict__ ebhh1,
    const float* __restrict__ oWhh0, const float* __restrict__ oWih1,
    const float* __restrict__ oWhh1, const float* __restrict__ obih1,
    const float* __restrict__ obhh1,
    float* __restrict__ hlast)                // [2][64]
{
    const int s    = blockIdx.x;
    const int wv   = threadIdx.x >> 6;
    const int lane = threadIdx.x & 63;

    __shared__ __align__(16) float h0buf[2][64];
    __shared__ __align__(16) float h1buf[2][64];
    __shared__ __align__(16) float qbuf[2][64];

    const float* Whh0 = s ? oWhh0 : eWhh0;
    const float* Wih1 = s ? oWih1 : eWih1;
    const float* Whh1 = s ? oWhh1 : eWhh1;
    const float  b1   = s ? (obih1[lane] + obhh1[lane])
                          : (ebih1[lane] + ebhh1[lane]);
    const float* p    = pre + s * T * 64;

    if (wv == 0) { h0buf[1][lane] = 0.f; h1buf[1][lane] = 0.f; }
    __syncthreads();

    if (wv == 0) {
        // -------- layer-0 wave: 64 (a) + 32 (q) FMAs --------
        float w0[64], wlo[32];
#pragma unroll
        for (int j = 0; j < 64; ++j) w0[j]  = Whh0[lane * 64 + j];
#pragma unroll
        for (int j = 0; j < 32; ++j) wlo[j] = Wih1[lane * 64 + j];

        float p_cur = p[lane];
        for (int t = 0; t <= T + 1; ++t) {
            if (t <= T) {
                float p_nxt = (t + 1 < T) ? p[(t + 1) * 64 + lane] : 0.f;  // prefetch
                const float4* hv = (const float4*)h0buf[(t - 1) & 1];

                // cache h0[t-1] in registers (64 VGPRs) — reused by q-part
                float4 v[16];
#pragma unroll
                for (int j4 = 0; j4 < 16; ++j4) v[j4] = hv[j4];

                // --- critical recurrence: a = p[t] + Whh0 @ h0[t-1] ---
                float a0 = p_cur, a1 = 0.f, a2 = 0.f, a3 = 0.f;
#pragma unroll
                for (int j4 = 0; j4 < 16; ++j4) {
                    a0 = fmaf(w0[4*j4+0], v[j4].x, a0);
                    a1 = fmaf(w0[4*j4+1], v[j4].y, a1);
                    a2 = fmaf(w0[4*j4+2], v[j4].z, a2);
                    a3 = fmaf(w0[4*j4+3], v[j4].w, a3);
                }
                if (t < T)
                    h0buf[t & 1][lane] = fast_tanh((a0 + a1) + (a2 + a3));  // publish ASAP

                // --- off-path: qp0[t-1] = b1 + Wih1[:,0:32] @ h0[t-1][0:32] ---
                float q0 = b1, q1 = 0.f, q2 = 0.f, q3 = 0.f;
#pragma unroll
                for (int j4 = 0; j4 < 8; ++j4) {
                    q0 = fmaf(wlo[4*j4+0], v[j4].x, q0);
                    q1 = fmaf(wlo[4*j4+1], v[j4].y, q1);
                    q2 = fmaf(wlo[4*j4+2], v[j4].z, q2);
                    q3 = fmaf(wlo[4*j4+3], v[j4].w, q3);
                }
                qbuf[(t - 1) & 1][lane] = (q0 + q1) + (q2 + q3);  // must run thru t==T (R4 bugfix)
                p_cur = p_nxt;
            }
            __syncthreads();
        }
    } else {
        // -------- layer-1 wave: 64 (c) + 32 (q) FMAs --------
        float whi[32], w1[64];
#pragma unroll
        for (int j = 0; j < 32; ++j) whi[j] = Wih1[lane * 64 + 32 + j];
#pragma unroll
        for (int j = 0; j < 64; ++j) w1[j]  = Whh1[lane * 64 + j];

        float qp1_cur = 0.f;   // qp1[t-2] during slot t
        float h1_last = 0.f;
        for (int t = 0; t <= T + 1; ++t) {
            // --- critical recurrence: h1[t-2] ---
            if (t >= 2) {
                const float4* h1v = (const float4*)h1buf[(t - 1) & 1];  // h1[t-3]
                float c0 = qbuf[(t - 2) & 1][lane] + qp1_cur;           // qp0+qp1 for t-2
                float c1 = 0.f, c2 = 0.f, c3 = 0.f;
#pragma unroll
                for (int j4 = 0; j4 < 16; ++j4) {
                    float4 u = h1v[j4];
                    c0 = fmaf(w1[4*j4+0], u.x, c0);  c1 = fmaf(w1[4*j4+1], u.y, c1);
                    c2 = fmaf(w1[4*j4+2], u.z, c2);  c3 = fmaf(w1[4*j4+3], u.w, c3);
                }
                float h1n = fast_tanh((c0 + c1) + (c2 + c3));
                h1buf[t & 1][lane] = h1n;            // publish ASAP
                h1_last = h1n;
            }
            // --- off-path: qp1[t-1] = Wih1[:,32:] @ h0[t-1][32:] ---
            if (t >= 1 && t <= T) {
                const float4* hv = ((const float4*)h0buf[(t - 1) & 1]) + 8;
                float q0 = 0.f, q1 = 0.f, q2 = 0.f, q3 = 0.f;
#pragma unroll
                for (int j4 = 0; j4 < 8; ++j4) {
                    float4 u = hv[j4];
                    q0 = fmaf(whi[4*j4+0], u.x, q0); q1 = fmaf(whi[4*j4+1], u.y, q1);
                    q2 = fmaf(whi[4*j4+2], u.z, q2); q3 = fmaf(whi[4*j4+3], u.w, q3);
                }
                qp1_cur = (q0 + q1) + (q2 + q3);
            } else if (t == 0) {
                qp1_cur = 0.f;
            }
            __syncthreads();
        }
        hlast[s * 64 + lane] = h1_last;
    }
}

// ---------------------------------------------------------------------------
// head: e0 = fce_w@hx + fce_b ; o0 = fco_w@hy + fco_b ; zz=[e0,o0,z];
//       h = relu(fc1_w@zz + fc1_b) ; out = fc2_w@h + fc2_b
// ---------------------------------------------------------------------------
__global__ void head_kernel(const float* __restrict__ hlast,   // [2][64]
                            const float* __restrict__ z,
                            const float* __restrict__ fce_w, const float* __restrict__ fce_b,
                            const float* __restrict__ fco_w, const float* __restrict__ fco_b,
                            const float* __restrict__ fc1_w, const float* __restrict__ fc1_b,
                            const float* __restrict__ fc2_w, const float* __restrict__ fc2_b,
                            float* __restrict__ out)            // [5]
{
    const int lane = threadIdx.x;   // 64 threads
    __shared__ float zz[9];
    __shared__ float hh[64];

    if (lane < 2) {
        float sacc = fce_b[lane];
        for (int j = 0; j < 64; ++j) sacc += fce_w[lane * 64 + j] * hlast[j];
        zz[lane] = sacc;
    } else if (lane < 4) {
        int r = lane - 2;
        float sacc = fco_b[r];
        for (int j = 0; j < 64; ++j) sacc += fco_w[r * 64 + j] * hlast[64 + j];
        zz[lane] = sacc;
    } else if (lane < 9) {
        zz[lane] = z[lane - 4];
    }
    __syncthreads();

    float sacc = fc1_b[lane];
#pragma unroll
    for (int j = 0; j < 9; ++j) sacc += fc1_w[lane * 9 + j] * zz[j];
    hh[lane] = fmaxf(sacc, 0.f);
    __syncthreads();

    if (lane < 5) {
        float o = fc2_b[lane];
        for (int i = 0; i < 64; ++i) o += fc2_w[lane * 64 + i] * hh[i];
        out[lane] = o;
    }
}

// ---------------------------------------------------------------------------
extern "C" void kernel_launch(void* const* d_in, const int* in_sizes, int n_in,
                              void* d_out, int out_size, void* d_ws, size_t ws_size,
                              hipStream_t stream)
{
    const float* x      = (const float*)d_in[0];
    const float* y      = (const float*)d_in[1];
    const float* z      = (const float*)d_in[2];
    const float* e_Wih0 = (const float*)d_in[3];
    const float* e_Whh0 = (const float*)d_in[4];
    const float* e_bih0 = (const float*)d_in[5];
    const float* e_bhh0 = (const float*)d_in[6];
    const float* e_Wih1 = (const float*)d_in[7];
    const float* e_Whh1 = (const float*)d_in[8];
    const float* e_bih1 = (const float*)d_in[9];
    const float* e_bhh1 = (const float*)d_in[10];
    const float* o_Wih0 = (const float*)d_in[11];
    const float* o_Whh0 = (const float*)d_in[12];
    const float* o_bih0 = (const float*)d_in[13];
    const float* o_bhh0 = (const float*)d_in[14];
    const float* o_Wih1 = (const float*)d_in[15];
    const float* o_Whh1 = (const float*)d_in[16];
    const float* o_bih1 = (const float*)d_in[17];
    const float* o_bhh1 = (const float*)d_in[18];
    const float* fce_w  = (const float*)d_in[19];
    const float* fce_b  = (const float*)d_in[20];
    const float* fco_w  = (const float*)d_in[21];
    const float* fco_b  = (const float*)d_in[22];
    const float* fc1_w  = (const float*)d_in[23];
    const float* fc1_b  = (const float*)d_in[24];
    const float* fc2_w  = (const float*)d_in[25];
    const float* fc2_b  = (const float*)d_in[26];

    float* pre   = (float*)d_ws;            // 2*T*64 floats = 2 MB
    float* hlast = pre + 2 * T * 64;        // 128 floats
    float* out   = (float*)d_out;

    prep_kernel<<<(2 * T * 64) / 256, 256, 0, stream>>>(
        x, y, e_Wih0, e_bih0, e_bhh0, o_Wih0, o_bih0, o_bhh0, pre);

    seq_kernel<<<2, 128, 0, stream>>>(
        pre,
        e_Whh0, e_Wih1, e_Whh1, e_bih1, e_bhh1,
        o_Whh0, o_Wih1, o_Whh1, o_bih1, o_bhh1,
        hlast);

    head_kernel<<<1, 64, 0, stream>>>(
        hlast, z, fce_w, fce_b, fco_w, fco_b, fc1_w, fc1_b, fc2_w, fc2_b, out);
}

// Round 7
// 1805.591 us; speedup vs baseline: 1.8033x; 1.5031x over previous
//
#include <hip/hip_runtime.h>

#define T 4096

// tanh(x) = 1 - 2/(exp(2x)+1). v_exp_f32 + v_rcp_f32, branch-free, ~30 cyc.
// Exonerated by R2 vs R3: identical absmax with/without -> error below bf16
// rounding even through 4096 recurrent steps. Saturates correctly at +/-1.
__device__ __forceinline__ float fast_tanh(float x) {
    float e = __expf(2.0f * x);
    float r = __builtin_amdgcn_rcpf(e + 1.0f);
    return fmaf(-2.0f, r, 1.0f);
}

// broadcast lane j's value of v to all lanes via v_readlane (SGPR result,
// usable directly as the scalar operand of v_fma_f32 — no LDS round-trip).
__device__ __forceinline__ float lane_bcast(float v, int j) {
    return __uint_as_float(__builtin_amdgcn_readlane(__float_as_uint(v), j));
}

// ---------------------------------------------------------------------------
// prep: pre[s][t][i] = b_ih0[i] + b_hh0[i] + sum_d W_ih0[i][d] * in[0,t,d]
// Only batch element 0 of x / y matters (reference uses e[0], o[0] only).
// ---------------------------------------------------------------------------
__global__ void prep_kernel(const float* __restrict__ x, const float* __restrict__ y,
                            const float* __restrict__ eW, const float* __restrict__ ebi,
                            const float* __restrict__ ebh,
                            const float* __restrict__ oW, const float* __restrict__ obi,
                            const float* __restrict__ obh,
                            float* __restrict__ pre)
{
    int idx = blockIdx.x * blockDim.x + threadIdx.x;   // 2*T*64 threads
    int i = idx & 63;
    int t = (idx >> 6) & (T - 1);
    int s = idx >> 18;
    const float* in = s ? y : x;          // batch 0 = first T*3 floats
    const float* W  = s ? oW : eW;        // [64][3]
    const float* bi = s ? obi : ebi;
    const float* bh = s ? obh : ebh;
    float v = bi[i] + bh[i]
            + W[i*3+0]*in[t*3+0] + W[i*3+1]*in[t*3+1] + W[i*3+2]*in[t*3+2];
    pre[idx] = v;
}

// ---------------------------------------------------------------------------
// seq: one block of 2 waves per RNN, 1 barrier per slot (R6's proven slot
// schedule). NEW vs R6: the recurrent operand (own-wave h) never touches LDS
// — it lives in one VGPR/lane and is broadcast via v_readlane straight into
// the FMA's scalar operand. LDS carries only the cross-wave flows, which all
// have >=1 slot of slack (h0 -> wave1's qp1; qp0 -> wave1's c-part).
//   wave0 @ slot t:  a = p[t] + Whh0@h0[t-1]  (readlane);  h0[t]=tanh(a), publish
//                    qp0[t-1] = b1 + Wih1[:,0:32]@h0[t-1][0:32]  (shares readlanes)
//   wave1 @ slot t:  h1[t-2] = tanh(qp0[t-2] + qp1[t-2] + Whh1@h1[t-3]) (readlane)
//                    qp1[t-1] = Wih1[:,32:]@h0[t-1][32:]  (LDS, 1-slot slack)
// ---------------------------------------------------------------------------
__global__ __launch_bounds__(128, 1) void seq_kernel(
    const float* __restrict__ pre,            // [2][T][64]
    const float* __restrict__ eWhh0, const float* __restrict__ eWih1,
    const float* __restrict__ eWhh1, const float* __restrict__ ebih1,
    const float* __restrict__ ebhh1,
    const float* __restrict__ oWhh0, const float* __restrict__ oWih1,
    const float* __restrict__ oWhh1, const float* __restrict__ obih1,
    const float* __restrict__ obhh1,
    float* __restrict__ hlast)                // [2][64]
{
    const int s    = blockIdx.x;
    const int wv   = threadIdx.x >> 6;
    const int lane = threadIdx.x & 63;

    __shared__ __align__(16) float h0lds[2][64];   // h0[t] for wave1 (slack 1)
    __shared__ __align__(16) float qbuf[2][64];    // qp0[t-1] for wave1 (slack 1)

    const float* Whh0 = s ? oWhh0 : eWhh0;
    const float* Wih1 = s ? oWih1 : eWih1;
    const float* Whh1 = s ? oWhh1 : eWhh1;
    const float  b1   = s ? (obih1[lane] + obhh1[lane])
                          : (ebih1[lane] + ebhh1[lane]);
    const float* p    = pre + s * T * 64;

    if (wv == 0) {
        // -------- layer-0 wave: 96 floats of weights (stays in VGPRs) --------
        float w0[64], wlo[32];
#pragma unroll
        for (int j = 0; j < 64; ++j) w0[j]  = Whh0[lane * 64 + j];
#pragma unroll
        for (int j = 0; j < 32; ++j) wlo[j] = Wih1[lane * 64 + j];

        float h0n   = 0.f;                    // h0[t-1], one VGPR, never in LDS
        float p_cur = p[lane];
        for (int t = 0; t <= T + 1; ++t) {
            if (t <= T) {
                float p_nxt = (t + 1 < T) ? p[(t + 1) * 64 + lane] : 0.f;
                float aa[4] = { p_cur, 0.f, 0.f, 0.f };
                float qq[4] = { b1,    0.f, 0.f, 0.f };
#pragma unroll
                for (int j = 0; j < 64; ++j) {
                    float hj = lane_bcast(h0n, j);           // h0[t-1][j]
                    aa[j & 3] = fmaf(w0[j], hj, aa[j & 3]);
                    if (j < 32) qq[j & 3] = fmaf(wlo[j], hj, qq[j & 3]);
                }
                // qp0[t-1] must run through t==T (R4 bugfix) — uses h0[T-1].
                qbuf[(t - 1) & 1][lane] = (qq[0] + qq[1]) + (qq[2] + qq[3]);
                if (t < T) {
                    h0n = fast_tanh((aa[0] + aa[1]) + (aa[2] + aa[3]));
                    h0lds[t & 1][lane] = h0n;                // publish for wave1
                }
                p_cur = p_nxt;
            }
            __syncthreads();
        }
    } else {
        // -------- layer-1 wave: 96 floats of weights --------
        float whi[32], w1[64];
#pragma unroll
        for (int j = 0; j < 32; ++j) whi[j] = Wih1[lane * 64 + 32 + j];
#pragma unroll
        for (int j = 0; j < 64; ++j) w1[j]  = Whh1[lane * 64 + j];

        float h1n     = 0.f;                  // h1[t-3] at slot t, one VGPR
        float qp1_cur = 0.f;                  // qp1[t-2] at slot t
        for (int t = 0; t <= T + 1; ++t) {
            // --- critical recurrence: h1[t-2] (readlane, no LDS) ---
            if (t >= 2) {
                float cc[4] = { qbuf[(t - 2) & 1][lane] + qp1_cur, 0.f, 0.f, 0.f };
#pragma unroll
                for (int j = 0; j < 64; ++j) {
                    float hj = lane_bcast(h1n, j);           // h1[t-3][j]
                    cc[j & 3] = fmaf(w1[j], hj, cc[j & 3]);
                }
                h1n = fast_tanh((cc[0] + cc[1]) + (cc[2] + cc[3]));  // h1[t-2]
            }
            // --- off-path: qp1[t-1] from h0[t-1][32:] (LDS, 1-slot slack) ---
            float nq = 0.f;
            if (t >= 1 && t <= T) {
                const float4* hv = ((const float4*)h0lds[(t - 1) & 1]) + 8;
                float q[4] = { 0.f, 0.f, 0.f, 0.f };
#pragma unroll
                for (int j4 = 0; j4 < 8; ++j4) {
                    float4 u = hv[j4];
                    q[0] = fmaf(whi[4*j4+0], u.x, q[0]);
                    q[1] = fmaf(whi[4*j4+1], u.y, q[1]);
                    q[2] = fmaf(whi[4*j4+2], u.z, q[2]);
                    q[3] = fmaf(whi[4*j4+3], u.w, q[3]);
                }
                nq = (q[0] + q[1]) + (q[2] + q[3]);
            }
            qp1_cur = nq;
            __syncthreads();
        }
        hlast[s * 64 + lane] = h1n;           // h1[T-1]
    }
}

// ---------------------------------------------------------------------------
// head: e0 = fce_w@hx + fce_b ; o0 = fco_w@hy + fco_b ; zz=[e0,o0,z];
//       h = relu(fc1_w@zz + fc1_b) ; out = fc2_w@h + fc2_b
// ---------------------------------------------------------------------------
__global__ void head_kernel(const float* __restrict__ hlast,   // [2][64]
                            const float* __restrict__ z,
                            const float* __restrict__ fce_w, const float* __restrict__ fce_b,
                            const float* __restrict__ fco_w, const float* __restrict__ fco_b,
                            const float* __restrict__ fc1_w, const float* __restrict__ fc1_b,
                            const float* __restrict__ fc2_w, const float* __restrict__ fc2_b,
                            float* __restrict__ out)            // [5]
{
    const int lane = threadIdx.x;   // 64 threads
    __shared__ float zz[9];
    __shared__ float hh[64];

    if (lane < 2) {
        float sacc = fce_b[lane];
        for (int j = 0; j < 64; ++j) sacc += fce_w[lane * 64 + j] * hlast[j];
        zz[lane] = sacc;
    } else if (lane < 4) {
        int r = lane - 2;
        float sacc = fco_b[r];
        for (int j = 0; j < 64; ++j) sacc += fco_w[r * 64 + j] * hlast[64 + j];
        zz[lane] = sacc;
    } else if (lane < 9) {
        zz[lane] = z[lane - 4];
    }
    __syncthreads();

    float sacc = fc1_b[lane];
#pragma unroll
    for (int j = 0; j < 9; ++j) sacc += fc1_w[lane * 9 + j] * zz[j];
    hh[lane] = fmaxf(sacc, 0.f);
    __syncthreads();

    if (lane < 5) {
        float o = fc2_b[lane];
        for (int i = 0; i < 64; ++i) o += fc2_w[lane * 64 + i] * hh[i];
        out[lane] = o;
    }
}

// ---------------------------------------------------------------------------
extern "C" void kernel_launch(void* const* d_in, const int* in_sizes, int n_in,
                              void* d_out, int out_size, void* d_ws, size_t ws_size,
                              hipStream_t stream)
{
    const float* x      = (const float*)d_in[0];
    const float* y      = (const float*)d_in[1];
    const float* z      = (const float*)d_in[2];
    const float* e_Wih0 = (const float*)d_in[3];
    const float* e_Whh0 = (const float*)d_in[4];
    const float* e_bih0 = (const float*)d_in[5];
    const float* e_bhh0 = (const float*)d_in[6];
    const float* e_Wih1 = (const float*)d_in[7];
    const float* e_Whh1 = (const float*)d_in[8];
    const float* e_bih1 = (const float*)d_in[9];
    const float* e_bhh1 = (const float*)d_in[10];
    const float* o_Wih0 = (const float*)d_in[11];
    const float* o_Whh0 = (const float*)d_in[12];
    const float* o_bih0 = (const float*)d_in[13];
    const float* o_bhh0 = (const float*)d_in[14];
    const float* o_Wih1 = (const float*)d_in[15];
    const float* o_Whh1 = (const float*)d_in[16];
    const float* o_bih1 = (const float*)d_in[17];
    const float* o_bhh1 = (const float*)d_in[18];
    const float* fce_w  = (const float*)d_in[19];
    const float* fce_b  = (const float*)d_in[20];
    const float* fco_w  = (const float*)d_in[21];
    const float* fco_b  = (const float*)d_in[22];
    const float* fc1_w  = (const float*)d_in[23];
    const float* fc1_b  = (const float*)d_in[24];
    const float* fc2_w  = (const float*)d_in[25];
    const float* fc2_b  = (const float*)d_in[26];

    float* pre   = (float*)d_ws;            // 2*T*64 floats = 2 MB
    float* hlast = pre + 2 * T * 64;        // 128 floats
    float* out   = (float*)d_out;

    prep_kernel<<<(2 * T * 64) / 256, 256, 0, stream>>>(
        x, y, e_Wih0, e_bih0, e_bhh0, o_Wih0, o_bih0, o_bhh0, pre);

    seq_kernel<<<2, 128, 0, stream>>>(
        pre,
        e_Whh0, e_Wih1, e_Whh1, e_bih1, e_bhh1,
        o_Whh0, o_Wih1, o_Whh1, o_bih1, o_bhh1,
        hlast);

    head_kernel<<<1, 64, 0, stream>>>(
        hlast, z, fce_w, fce_b, fco_w, fco_b, fc1_w, fc1_b, fc2_w, fc2_b, out);
}